// Round 13
// baseline (172.568 us; speedup 1.0000x reference)
//
#include <hip/hip_runtime.h>
#include <math.h>

// B=8, C=128, N=4096, d=16, groups=32
// R13 attn: V staged via global_load_lds DMA (width 16), VS=16 linear rows
//   (DMA needs base+lane*16 dest; 2-way read aliasing is free per m136).
//   Removes per-tile: 16 reg loads + 16 ds_writes + write-port conflicts
//   (R12's 4.26M conflict cycles were the staging writes).
//   Block 256 thr (4 waves) = (batch, 64-i tile), grid 512, XCD-pinned,
//   double-buffered, 1 barrier/tile. P in registers (half-wave exchange),
//   K direct global, Q from transposed [B,16,N].
//   Epilogue: 2-pass f32 overlay combine (fits 32 KB V buffer).
// prep merged into gn_stats (one fewer launch).

typedef short v8s __attribute__((ext_vector_type(8)));   // 8 bf16 = 4 VGPRs
typedef float v16f __attribute__((ext_vector_type(16))); // 32x32 acc

__device__ __forceinline__ unsigned short f2bf_rne(float f) {
  unsigned u = __float_as_uint(f);
  u += 0x7fffu + ((u >> 16) & 1u);
  return (unsigned short)(u >> 16);
}

__device__ __forceinline__ v8s mk8(unsigned a, unsigned b, unsigned c, unsigned d) {
  union { unsigned u[4]; v8s s; } x;
  x.u[0] = a; x.u[1] = b; x.u[2] = c; x.u[3] = d;
  return x.s;
}

// pack two fp32 -> dword of 2 bf16 (truncation) in ONE v_perm_b32
__device__ __forceinline__ unsigned pack_trunc(float hi, float lo) {
  return __builtin_amdgcn_perm(__float_as_uint(hi), __float_as_uint(lo), 0x07060302u);
}

// async global->LDS DMA, 16 B/lane; lds dest must be wave-uniform base
__device__ __forceinline__ void cp16_async(const unsigned short* g, unsigned short* l) {
  __builtin_amdgcn_global_load_lds(
      (const __attribute__((address_space(1))) unsigned int*)g,
      (__attribute__((address_space(3))) unsigned int*)l, 16, 0, 0);
}

// tiled V element index: [b][j>>4][c][j&15]
#define VT(b, n, c) (((((size_t)(b) * 256 + ((n) >> 4)) << 7) + (c)) * 16 + ((n) & 15))

// ws byte offsets
#define WSB_MURS   0u
#define WSB_WCATB  4096u       // 160*128 bf16 = 40960
#define WSB_BCAT   49152u      // 160 f32
#define WSB_PWB    65536u      // 128*128 bf16 = 32768
#define WSB_QBF    131072u     // Q^T [B,16,N] bf16 = 1 MB
#define WSB_KBF    1310720u    // K [B,N,16] bf16 = 1 MB
#define WSB_VBF    2621440u    // 8 MB (tiled)
#define WSB_ABF    11534336u   // 8 MB

// ---------------------------------------------------------------------------
// gn_stats + prep fused. Grid 256 x 512 thr. gn part: XCD-swizzled (b,g).
// prep part: linear idx covers 160*128 + 160 + 128*128 = 36960 elements.
// ---------------------------------------------------------------------------
__global__ __launch_bounds__(512)
void gnprep_kernel(const float* __restrict__ x, float* __restrict__ mu_rs,
                   const float* __restrict__ qw, const float* __restrict__ qb,
                   const float* __restrict__ kw, const float* __restrict__ kb,
                   const float* __restrict__ vw, const float* __restrict__ vb,
                   const float* __restrict__ pw,
                   unsigned short* __restrict__ wcatb, float* __restrict__ bcat,
                   unsigned short* __restrict__ pwb) {
  const int id = blockIdx.x;
  // ---- prep part ----
  {
    const float qs = 0.36067376022224085f;  // 0.25 * log2(e)
    int idx = id * 512 + threadIdx.x;
    if (idx < 160 * 128) {
      int o = idx >> 7, c = idx & 127;
      float val;
      if (o < 16)       val = qw[o * 128 + c] * qs;
      else if (o < 32)  val = kw[(o - 16) * 128 + c];
      else              val = vw[(o - 32) * 128 + c];
      wcatb[idx] = f2bf_rne(val);
    } else if (idx < 160 * 128 + 160) {
      int o = idx - 160 * 128;
      bcat[o] = (o < 16) ? qb[o] * qs : (o < 32) ? kb[o - 16] : vb[o - 32];
    } else if (idx < 160 * 128 + 160 + 128 * 128) {
      int j = idx - (160 * 128 + 160);
      pwb[j] = f2bf_rne(pw[j]);
    }
  }
  // ---- gn part ----
  const int bg = (id & 7) * 32 + (id >> 3);   // XCD swizzle: batch = id & 7
  const float4* xp = (const float4*)(x + (size_t)bg * 16384);
  float s = 0.f, ss = 0.f;
#pragma unroll
  for (int u = 0; u < 8; ++u) {
    int i = threadIdx.x + u * 512;
    float4 v = xp[i];
    s  += v.x + v.y + v.z + v.w;
    ss += v.x * v.x + v.y * v.y + v.z * v.z + v.w * v.w;
  }
  for (int off = 32; off > 0; off >>= 1) {
    s  += __shfl_down(s, off, 64);
    ss += __shfl_down(ss, off, 64);
  }
  __shared__ float red[16];
  int lane = threadIdx.x & 63, wid = threadIdx.x >> 6;
  if (lane == 0) { red[wid * 2] = s; red[wid * 2 + 1] = ss; }
  __syncthreads();
  if (threadIdx.x == 0) {
    float S = 0.f, SS = 0.f;
    for (int w = 0; w < 8; ++w) { S += red[w * 2]; SS += red[w * 2 + 1]; }
    float mu  = S * (1.0f / 16384.0f);
    float var = SS * (1.0f / 16384.0f) - mu * mu;
    float rs  = rsqrtf(var + 1e-5f);
    mu_rs[bg * 2]     = mu;
    mu_rs[bg * 2 + 1] = rs;
  }
}

// ---------------------------------------------------------------------------
// QKV as MFMA GEMM, GN fused. Block 512 thr (8 waves), n-tile 64.
// All 64 x-loads hoisted up front. Q stored TRANSPOSED [B,16,N]. XCD-pinned.
// ---------------------------------------------------------------------------
__global__ __launch_bounds__(512)
void qkv_kernel(const float* __restrict__ x, const float* __restrict__ gnw,
                const float* __restrict__ gnb, const float* __restrict__ mu_rs,
                const unsigned short* __restrict__ wcatb, const float* __restrict__ bcat,
                unsigned short* __restrict__ qTb, unsigned short* __restrict__ kbf,
                unsigned short* __restrict__ vbf) {
  __shared__ float scs[128], shs[128], bsh[160];
  const int id = blockIdx.x;
  const int b = id & 7, nb = (id >> 3) << 6;   // XCD-pinned batch
  const int t = threadIdx.x;
  const int w = t >> 6, lane = t & 63, h = lane >> 5, l = lane & 31;
  const int nsub = w & 1, og = w >> 1;
  if (t < 128) {
    float mu = mu_rs[(b * 32 + (t >> 2)) * 2];
    float rs = mu_rs[(b * 32 + (t >> 2)) * 2 + 1];
    float gw = gnw[t], gb = gnb[t];
    scs[t] = rs * gw; shs[t] = gb - mu * rs * gw;
  }
  if (t < 160) bsh[t] = bcat[t];
  __syncthreads();

  const int n = nb + nsub * 32 + l;
  const float* xb = x + ((size_t)b * 128 << 12);
  const int otbase = (og == 0) ? 0 : og + 1; // ot index of acc[0]

  // hoist all 64 x loads (8 ks-steps x 8 channels) for max MLP
  float xv[64];
#pragma unroll
  for (int ks = 0; ks < 8; ++ks)
#pragma unroll
    for (int p = 0; p < 8; ++p)
      xv[ks * 8 + p] = xb[((size_t)(ks * 16 + 8 * h + p) << 12) + n];

  v16f acc[2];
#pragma unroll
  for (int a2 = 0; a2 < 2; ++a2)
#pragma unroll
    for (int r = 0; r < 16; ++r) acc[a2][r] = 0.f;

#pragma unroll
  for (int ks = 0; ks < 8; ++ks) {
    const int c0 = ks * 16 + 8 * h;
    unsigned fd[4];
#pragma unroll
    for (int p = 0; p < 4; ++p) {
      int ca = c0 + 2 * p;
      float h0 = xv[ks * 8 + 2 * p]     * scs[ca]     + shs[ca];
      float h1 = xv[ks * 8 + 2 * p + 1] * scs[ca + 1] + shs[ca + 1];
      fd[p] = (unsigned)f2bf_rne(h0) | ((unsigned)f2bf_rne(h1) << 16);
    }
    v8s bf = mk8(fd[0], fd[1], fd[2], fd[3]);
    {
      v8s af = *(const v8s*)(wcatb + (otbase * 32 + l) * 128 + ks * 16 + 8 * h);
      acc[0] = __builtin_amdgcn_mfma_f32_32x32x16_bf16(af, bf, acc[0], 0, 0, 0);
    }
    if (og == 0) {
      v8s af = *(const v8s*)(wcatb + (32 + l) * 128 + ks * 16 + 8 * h);
      acc[1] = __builtin_amdgcn_mfma_f32_32x32x16_bf16(af, bf, acc[1], 0, 0, 0);
    }
  }

  // epilogue
  if (og == 0) {
    const size_t nqk = ((size_t)b * 4096 + n) << 4;
#pragma unroll
    for (int r = 0; r < 16; ++r) {
      int o = 4 * h + (r & 3) + 8 * (r >> 2);
      unsigned short bv = f2bf_rne(acc[0][r] + bsh[o]);
      if (o < 16) qTb[((size_t)(b * 16 + o) << 12) + n] = bv;   // coalesced
      else        kbf[nqk + o - 16] = bv;
    }
#pragma unroll
    for (int r = 0; r < 16; ++r) {
      int o = 32 + 4 * h + (r & 3) + 8 * (r >> 2);
      vbf[VT(b, n, o - 32)] = f2bf_rne(acc[1][r] + bsh[o]);
    }
  } else {
#pragma unroll
    for (int r = 0; r < 16; ++r) {
      int o = otbase * 32 + 4 * h + (r & 3) + 8 * (r >> 2);
      vbf[VT(b, n, o - 32)] = f2bf_rne(acc[0][r] + bsh[o]);
    }
  }
}

// ---------------------------------------------------------------------------
// R13 flash attention. 256 thr (4 waves), grid 512, XCD-pinned.
// V double-buffered via global_load_lds DMA; rows 16 shorts, linear.
// ---------------------------------------------------------------------------
__global__ __launch_bounds__(256)
void attn_kernel(const unsigned short* __restrict__ qTb,
                 const unsigned short* __restrict__ kbf,
                 const unsigned short* __restrict__ vbf,
                 unsigned short* __restrict__ abf) {
  __shared__ alignas(16) unsigned short smem[2][8192];   // 32768 B
  __shared__ float l_lds[64];

  const int id = blockIdx.x;
  const int b = id & 7, i0 = (id >> 3) << 6;   // XCD-pinned batch, 64-i tile
  const int t = threadIdx.x;
  const int w = t >> 6, lane = t & 63, h = lane >> 5, l = lane & 31;
  const int jsub = w & 1, ihalf = w >> 1;

  const unsigned short* kg = kbf + ((size_t)b << 16);
  const unsigned short* vg = vbf + ((size_t)b << 19);

  // Q B-frag from Q^T [B,16,N]: 8 coalesced b16 loads, once per kernel
  const int iglob = i0 + ihalf * 32 + l;
  unsigned qd[4];
#pragma unroll
  for (int e = 0; e < 4; ++e) {
    unsigned lo = qTb[((size_t)(b * 16 + 8 * h + 2 * e) << 12) + iglob];
    unsigned hi = qTb[((size_t)(b * 16 + 8 * h + 2 * e + 1) << 12) + iglob];
    qd[e] = lo | (hi << 16);
  }
  const v8s qf = mk8(qd[0], qd[1], qd[2], qd[3]);

  v16f zc;
#pragma unroll
  for (int r = 0; r < 16; ++r) zc[r] = 0.f;
  v16f acc[4];
#pragma unroll
  for (int ct = 0; ct < 4; ++ct)
#pragma unroll
    for (int r = 0; r < 16; ++r) acc[ct][r] = 0.f;
  float ls = 0.f;

  // DMA geometry: wave w stages its quarter (4 KB) as 4 x 1 KB instrs.
  // global src: vg + tile*8192 + w*2048 + u*512 + lane*8 (shorts)
  // lds dest (wave-uniform): buf + w*2048 + u*512
  if (t < 64) l_lds[t] = 0.f;

  // prologue: DMA tile 0 into buf 0
#pragma unroll
  for (int u = 0; u < 4; ++u)
    cp16_async(vg + (size_t)(w * 2048 + u * 512) + lane * 8,
               &smem[0][w * 2048 + u * 512]);
  __syncthreads();   // drains vmcnt before barrier -> DMA complete

  for (int tile = 0; tile < 64; ++tile) {
    const int tn = (tile + 1) & 63;   // wrap: harmless reload on last iter
    unsigned short* const cur = smem[tile & 1];
    unsigned short* const nxt = smem[(tile + 1) & 1];

    // fire next tile's DMA (stays in flight through this tile's compute)
#pragma unroll
    for (int u = 0; u < 4; ++u)
      cp16_async(vg + (size_t)tn * 8192 + (w * 2048 + u * 512) + lane * 8,
                 &nxt[w * 2048 + u * 512]);

    // K A-frag direct from global (coalesced 1KB)
    v8s kf = *(const v8s*)(kg + (((size_t)(tile * 64 + jsub * 32 + l)) << 4) + 8 * h);

    // QK: S^T patch (rows j, cols i) -> P in regs
    v16f st = __builtin_amdgcn_mfma_f32_32x32x16_bf16(kf, qf, zc, 0, 0, 0);
    float pe[16];
#pragma unroll
    for (int r = 0; r < 16; ++r) { pe[r] = __builtin_amdgcn_exp2f(st[r]); ls += pe[r]; }
    unsigned G[8];
#pragma unroll
    for (int g = 0; g < 4; ++g) {
      G[2 * g]     = pack_trunc(pe[4 * g + 1], pe[4 * g]);
      G[2 * g + 1] = pack_trunc(pe[4 * g + 3], pe[4 * g + 2]);
    }
    // half-wave exchange (proven mapping): 4 shfl + selects
    unsigned S0 = h ? G[0] : G[2], S1 = h ? G[1] : G[3];
    unsigned S2 = h ? G[4] : G[6], S3 = h ? G[5] : G[7];
    unsigned R0 = (unsigned)__shfl_xor((int)S0, 32, 64);
    unsigned R1 = (unsigned)__shfl_xor((int)S1, 32, 64);
    unsigned R2 = (unsigned)__shfl_xor((int)S2, 32, 64);
    unsigned R3 = (unsigned)__shfl_xor((int)S3, 32, 64);
    v8s pf0 = h ? mk8(R0, R1, G[2], G[3]) : mk8(G[0], G[1], R0, R1);
    v8s pf1 = h ? mk8(R2, R3, G[6], G[7]) : mk8(G[4], G[5], R2, R3);

    // PV from cur (VS=16: 2-way read aliasing = free)
#pragma unroll
    for (int ct = 0; ct < 4; ++ct) {
      v8s vf0 = *(const v8s*)(&cur[((jsub * 2) * 128 + ct * 32 + l) * 16 + 8 * h]);
      v8s vf1 = *(const v8s*)(&cur[((jsub * 2 + 1) * 128 + ct * 32 + l) * 16 + 8 * h]);
      acc[ct] = __builtin_amdgcn_mfma_f32_32x32x16_bf16(vf0, pf0, acc[ct], 0, 0, 0);
      acc[ct] = __builtin_amdgcn_mfma_f32_32x32x16_bf16(vf1, pf1, acc[ct], 0, 0, 0);
    }

    __syncthreads();   // PV done with cur; DMA into nxt drained
  }

  // ---- epilogue: 2-pass combine (overlay fits 32 KB buffer) ----
  atomicAdd(&l_lds[ihalf * 32 + l], ls);
  __syncthreads();
  float* const ov = (float*)smem;   // pass uses 4 groups x 32 rows x 36 f32
  const float li = 1.f / l_lds[ihalf * 32 + l];
#pragma unroll
  for (int pass = 0; pass < 2; ++pass) {
    const int cta = pass * 2, ctb = pass * 2 + 1;
    if (jsub == 1) {
#pragma unroll
      for (int k = 0; k < 2; ++k) {
        const int ct = pass * 2 + k;
#pragma unroll
        for (int q = 0; q < 4; ++q) {
          float4 v4 = {acc[ct][4 * q], acc[ct][4 * q + 1],
                       acc[ct][4 * q + 2], acc[ct][4 * q + 3]};
          *(float4*)&ov[((k * 2 + ihalf) * 32 + l) * 36 + 4 * h + 8 * q] = v4;
        }
      }
    }
    __syncthreads();
    if (jsub == 0) {
#pragma unroll
      for (int k = 0; k < 2; ++k) {
        const int ct = pass * 2 + k;
#pragma unroll
        for (int q = 0; q < 4; ++q) {
          float4 v4 = *(float4*)&ov[((k * 2 + ihalf) * 32 + l) * 36 + 4 * h + 8 * q];
          acc[ct][4 * q]     += v4.x;
          acc[ct][4 * q + 1] += v4.y;
          acc[ct][4 * q + 2] += v4.z;
          acc[ct][4 * q + 3] += v4.w;
        }
#pragma unroll
        for (int r = 0; r < 16; ++r) {
          int c = ct * 32 + 4 * h + (r & 3) + 8 * (r >> 2);
          abf[((size_t)(b * 128 + c) << 12) + (size_t)(i0 + ihalf * 32 + l)] =
              f2bf_rne(acc[ct][r] * li);
        }
      }
    }
    __syncthreads();
  }
}

// ---------------------------------------------------------------------------
// proj as MFMA GEMM + bias + residual. Block 512 thr (8 waves), n-tile 64:
// nsub = w&1, ot = w>>1. All 64 abf loads hoisted up front. XCD-pinned grid.
// ---------------------------------------------------------------------------
__global__ __launch_bounds__(512)
void proj_kernel(const unsigned short* __restrict__ abf, const unsigned short* __restrict__ pwb,
                 const float* __restrict__ pb, const float* __restrict__ x,
                 float* __restrict__ out) {
  __shared__ float pbs[128];
  const int id = blockIdx.x;
  const int b = id & 7, nb = (id >> 3) << 6;   // XCD-pinned batch
  const int t = threadIdx.x;
  const int w = t >> 6, lane = t & 63, h = lane >> 5, l = lane & 31;
  const int nsub = w & 1, ot = w >> 1;
  if (t < 128) pbs[t] = pb[t];
  __syncthreads();

  const int n = nb + nsub * 32 + l;
  const unsigned short* ab = abf + (((size_t)b * 128) << 12);

  // hoist all 64 abf loads
  unsigned short av[64];
#pragma unroll
  for (int ks = 0; ks < 8; ++ks)
#pragma unroll
    for (int p = 0; p < 8; ++p)
      av[ks * 8 + p] = ab[((size_t)(ks * 16 + 8 * h + p) << 12) + n];

  v16f acc;
#pragma unroll
  for (int r = 0; r < 16; ++r) acc[r] = 0.f;

#pragma unroll
  for (int ks = 0; ks < 8; ++ks) {
    unsigned fd[4];
#pragma unroll
    for (int p = 0; p < 4; ++p)
      fd[p] = (unsigned)av[ks * 8 + 2 * p] | ((unsigned)av[ks * 8 + 2 * p + 1] << 16);
    v8s bf = mk8(fd[0], fd[1], fd[2], fd[3]);
    v8s af = *(const v8s*)(pwb + (ot * 32 + l) * 128 + ks * 16 + 8 * h);
    acc = __builtin_amdgcn_mfma_f32_32x32x16_bf16(af, bf, acc, 0, 0, 0);
  }

#pragma unroll
  for (int r = 0; r < 16; ++r) {
    int e = ot * 32 + 4 * h + (r & 3) + 8 * (r >> 2);
    size_t idx = ((size_t)(b * 128 + e) << 12) + n;
    out[idx] = acc[r] + pbs[e] + x[idx];
  }
}

// ---------------------------------------------------------------------------
extern "C" void kernel_launch(void* const* d_in, const int* in_sizes, int n_in,
                              void* d_out, int out_size, void* d_ws, size_t ws_size,
                              hipStream_t stream) {
  const float* x   = (const float*)d_in[0];
  const float* gnw = (const float*)d_in[1];
  const float* gnb = (const float*)d_in[2];
  const float* qw  = (const float*)d_in[3];
  const float* qb  = (const float*)d_in[4];
  const float* kw  = (const float*)d_in[5];
  const float* kb  = (const float*)d_in[6];
  const float* vw  = (const float*)d_in[7];
  const float* vb  = (const float*)d_in[8];
  const float* pw  = (const float*)d_in[9];
  const float* pb  = (const float*)d_in[10];
  float* out = (float*)d_out;
  char* ws = (char*)d_ws;

  float* mu_rs = (float*)(ws + WSB_MURS);
  unsigned short* wcatb = (unsigned short*)(ws + WSB_WCATB);
  float* bcat = (float*)(ws + WSB_BCAT);
  unsigned short* pwb = (unsigned short*)(ws + WSB_PWB);
  unsigned short* qTb = (unsigned short*)(ws + WSB_QBF);
  unsigned short* kbf = (unsigned short*)(ws + WSB_KBF);
  unsigned short* vbf = (unsigned short*)(ws + WSB_VBF);
  unsigned short* abf = (unsigned short*)(ws + WSB_ABF);

  hipLaunchKernelGGL(gnprep_kernel, dim3(256), dim3(512), 0, stream,
                     x, mu_rs, qw, qb, kw, kb, vw, vb, pw, wcatb, bcat, pwb);
  hipLaunchKernelGGL(qkv_kernel, dim3(512), dim3(512), 0, stream,
                     x, gnw, gnb, mu_rs, wcatb, bcat, qTb, kbf, vbf);
  hipLaunchKernelGGL(attn_kernel, dim3(512), dim3(256), 0, stream,
                     qTb, kbf, vbf, abf);
  hipLaunchKernelGGL(proj_kernel, dim3(512), dim3(512), 0, stream,
                     abf, pwb, pb, x, out);
}